// Round 1
// baseline (1872.830 us; speedup 1.0000x reference)
//
#include <hip/hip_runtime.h>

typedef unsigned short u16;
typedef short s16x8 __attribute__((ext_vector_type(8)));
typedef float f32x4 __attribute__((ext_vector_type(4)));
typedef u16 u16x4 __attribute__((ext_vector_type(4)));

#define DEV static __device__ __forceinline__

// ---------- bf16 helpers (RTNE) ----------
DEV u16 f2bf(float x){
    union { float f; unsigned u; } v; v.f = x;
    unsigned r = v.u + 0x7FFFu + ((v.u >> 16) & 1u);
    return (u16)(r >> 16);
}
DEV float bf2f(u16 h){
    union { unsigned u; float f; } v; v.u = ((unsigned)h) << 16; return v.f;
}
DEV void split_bf(float x, u16& h, u16& l){
    h = f2bf(x);
    l = f2bf(x - bf2f(h));
}

// =====================================================================
// K1: supports = softmax(relu(E E^T)) row-wise -> hi/lo bf16 pair
// =====================================================================
__global__ __launch_bounds__(256) void k_supports(const float* __restrict__ E,
                                                  u16* __restrict__ Sh, u16* __restrict__ Sl)
{
    const int n = blockIdx.x, tid = threadIdx.x;
    const int w = tid >> 6, lane = tid & 63;
    __shared__ float red[8];

    float en[10];
    #pragma unroll
    for (int d = 0; d < 10; d++) en[d] = E[n*10 + d];

    float v[8];
    #pragma unroll
    for (int i = 0; i < 8; i++){
        int m = tid + i*256;
        const float* em = E + m*10;
        float s = 0.f;
        #pragma unroll
        for (int d = 0; d < 10; d++) s += en[d]*em[d];
        v[i] = fmaxf(s, 0.f);
    }
    float mx = v[0];
    #pragma unroll
    for (int i = 1; i < 8; i++) mx = fmaxf(mx, v[i]);
    #pragma unroll
    for (int off = 32; off > 0; off >>= 1) mx = fmaxf(mx, __shfl_xor(mx, off));
    if (lane == 0) red[w] = mx;
    __syncthreads();
    mx = fmaxf(fmaxf(red[0], red[1]), fmaxf(red[2], red[3]));
    __syncthreads();

    float sum = 0.f;
    #pragma unroll
    for (int i = 0; i < 8; i++){ v[i] = __expf(v[i] - mx); sum += v[i]; }
    #pragma unroll
    for (int off = 32; off > 0; off >>= 1) sum += __shfl_xor(sum, off);
    if (lane == 0) red[4 + w] = sum;
    __syncthreads();
    sum = red[4] + red[5] + red[6] + red[7];
    float inv = 1.f / sum;

    #pragma unroll
    for (int i = 0; i < 8; i++){
        float p = v[i] * inv;
        u16 h, l; split_bf(p, h, l);
        int m = tid + i*256;
        Sh[n*2048 + m] = h;
        Sl[n*2048 + m] = l;
    }
}

// =====================================================================
// K2: prep — weight pools -> [jc][d][o][k] hi/lo (per-(jc,d) tile is a
//     CONTIGUOUS block), biases E@bpool, X_gate^T pack.
// =====================================================================
__global__ __launch_bounds__(256) void k_prep(const float* __restrict__ E,
    const float* __restrict__ gwp, const float* __restrict__ gbp,
    const float* __restrict__ uwp, const float* __restrict__ ubp,
    const float* __restrict__ x,   const float* __restrict__ state,
    u16* __restrict__ wgh, u16* __restrict__ wgl,
    u16* __restrict__ wuh, u16* __restrict__ wul,
    float* __restrict__ bg, float* __restrict__ bu,
    u16* __restrict__ xth, u16* __restrict__ xtl)
{
    long idx = (long)blockIdx.x*256 + threadIdx.x;
    if (idx < 491520){                               // gate w -> [jc][d][128 o][32 k]
        int kk = (int)(idx & 31);
        int o  = (int)((idx >> 5) & 127);
        int r2 = (int)(idx >> 12);                   // 0..119
        int d = r2 % 10, jc = r2 / 10;
        int j = jc*32 + kk;                          // 0..383
        int k = j >> 7, i = j & 127;
        float v = gwp[(((d*3 + k)*128) + i)*128 + o];
        u16 h,l; split_bf(v,h,l); wgh[idx]=h; wgl[idx]=l;
    } else if (idx < 737280){                        // upd w -> [jc][d][64 o][32 k]
        long t = idx - 491520;
        int kk = (int)(t & 31);
        int o  = (int)((t >> 5) & 63);
        int r2 = (int)(t >> 11);                     // 0..119
        int d = r2 % 10, jc = r2 / 10;
        int j = jc*32 + kk;
        int k = j >> 7, i = j & 127;
        float v = uwp[(((d*3 + k)*128) + i)*64 + o];
        u16 h,l; split_bf(v,h,l); wuh[t]=h; wul[t]=l;
    } else if (idx < 999424){                        // bias_g [2048][128]
        long t = idx - 737280; int n = (int)(t >> 7), o = (int)(t & 127);
        float s = 0.f;
        #pragma unroll
        for (int d = 0; d < 10; d++) s += E[n*10+d]*gbp[d*128+o];
        bg[t] = s;
    } else if (idx < 1130496){                       // bias_u [2048][64]
        long t = idx - 999424; int n = (int)(t >> 6), o = (int)(t & 63);
        float s = 0.f;
        #pragma unroll
        for (int d = 0; d < 10; d++) s += E[n*10+d]*ubp[d*64+o];
        bu[t] = s;
    } else if (idx < 5324800){                       // X_gate^T pack
        long t = idx - 1130496;
        int colG = (int)(t >> 11), m = (int)(t & 2047);
        int b = colG >> 7, c = colG & 127;
        float v = (c < 64) ? x[((long)(b*2048)+m)*64 + c]
                           : state[((long)(b*2048)+m)*64 + c - 64];
        u16 h,l; split_bf(v,h,l); xth[t]=h; xtl[t]=l;
    }
}

// =====================================================================
// Diffusion GEMM  C[i][j] = sum_k A[i][k] * Bt[j][k], 3-term split MFMA.
// 64x128 tile -> 512 blocks = 2 blocks/CU.
// EPI=0: store t-layout hi/lo + row-major f32. EPI=1: 2*acc-X, row f32.
// =====================================================================
template<int EPI>
__global__ __launch_bounds__(256) void k_gemm(
    const u16* __restrict__ Ah, const u16* __restrict__ Al,
    const u16* __restrict__ Bh, const u16* __restrict__ Bl,
    u16* __restrict__ Oth, u16* __restrict__ Otl, float* __restrict__ Orow,
    const u16* __restrict__ Xh, const u16* __restrict__ Xl)
{
    __shared__ u16 AsH[64*40], AsL[64*40], BsH[128*40], BsL[128*40];
    const int tid = threadIdx.x;
    const int bm = (blockIdx.x & 31) << 6;   // 32 row-tiles of 64 (node rows)
    const int bn = (blockIdx.x >> 5) << 7;   // 16 col-tiles of 128 (colG)
    const int w = tid >> 6, lane = tid & 63;
    const int wn = w << 5;                   // 32 cols per wave
    const int lr = lane & 15, lk = lane >> 4;

    const int ar = tid >> 2, ac = (tid & 3) << 3;    // staging: 64 rows x 32 cols
    const long gA  = (long)(bm + ar)*2048 + ac;
    const long gB0 = (long)(bn + ar)*2048 + ac;
    const long gB1 = (long)(bn + ar + 64)*2048 + ac;
    const int lA  = ar*40 + ac;
    const int lB0 = ar*40 + ac, lB1 = (ar + 64)*40 + ac;

    f32x4 acc[4][2];
    const f32x4 Z4 = {0.f, 0.f, 0.f, 0.f};
    #pragma unroll
    for (int i = 0; i < 4; i++)
        #pragma unroll
        for (int j = 0; j < 2; j++) acc[i][j] = Z4;

    s16x8 rah  = *(const s16x8*)(Ah + gA);
    s16x8 ral  = *(const s16x8*)(Al + gA);
    s16x8 rbh0 = *(const s16x8*)(Bh + gB0), rbh1 = *(const s16x8*)(Bh + gB1);
    s16x8 rbl0 = *(const s16x8*)(Bl + gB0), rbl1 = *(const s16x8*)(Bl + gB1);

    for (int k0 = 0; k0 < 2048; k0 += 32){
        __syncthreads();
        *(s16x8*)&AsH[lA]  = rah;  *(s16x8*)&AsL[lA]  = ral;
        *(s16x8*)&BsH[lB0] = rbh0; *(s16x8*)&BsH[lB1] = rbh1;
        *(s16x8*)&BsL[lB0] = rbl0; *(s16x8*)&BsL[lB1] = rbl1;
        __syncthreads();
        if (k0 + 32 < 2048){
            long ka = k0 + 32;
            rah  = *(const s16x8*)(Ah + gA + ka);
            ral  = *(const s16x8*)(Al + gA + ka);
            rbh0 = *(const s16x8*)(Bh + gB0 + ka); rbh1 = *(const s16x8*)(Bh + gB1 + ka);
            rbl0 = *(const s16x8*)(Bl + gB0 + ka); rbl1 = *(const s16x8*)(Bl + gB1 + ka);
        }
        #pragma unroll
        for (int s = 0; s < 3; s++){
            const u16* Ap = (s == 1) ? AsL : AsH;
            const u16* Bp = (s == 2) ? BsL : BsH;
            s16x8 af[4], bfv[2];
            #pragma unroll
            for (int mi = 0; mi < 4; mi++)
                af[mi] = *(const s16x8*)&Ap[(mi*16 + lr)*40 + lk*8];
            #pragma unroll
            for (int ni = 0; ni < 2; ni++)
                bfv[ni] = *(const s16x8*)&Bp[(wn + ni*16 + lr)*40 + lk*8];
            #pragma unroll
            for (int mi = 0; mi < 4; mi++)
                #pragma unroll
                for (int ni = 0; ni < 2; ni++)
                    acc[mi][ni] = __builtin_amdgcn_mfma_f32_16x16x32_bf16(
                        af[mi], bfv[ni], acc[mi][ni], 0, 0, 0);
        }
    }

    #pragma unroll
    for (int mi = 0; mi < 4; mi++){
        #pragma unroll
        for (int ni = 0; ni < 2; ni++){
            int i0 = bm + mi*16 + lk*4;          // node (4 consecutive)
            int j  = bn + wn + ni*16 + lr;       // colG
            f32x4 v = acc[mi][ni];
            if constexpr (EPI){
                u16x4 xh = *(const u16x4*)(Xh + (long)j*2048 + i0);
                u16x4 xl = *(const u16x4*)(Xl + (long)j*2048 + i0);
                #pragma unroll
                for (int r = 0; r < 4; r++)
                    v[r] = 2.f*v[r] - (bf2f(xh[r]) + bf2f(xl[r]));
            }
            int bb = j >> 7, cc = j & 127;
            float* rp = Orow + ((long)bb*2048 + i0)*128 + cc;
            #pragma unroll
            for (int r = 0; r < 4; r++) rp[(long)r*128] = v[r];
            if constexpr (!EPI){
                u16x4 oh, ol;
                #pragma unroll
                for (int r = 0; r < 4; r++){ u16 h,l; split_bf(v[r], h, l); oh[r]=h; ol[r]=l; }
                *(u16x4*)(Oth + (long)j*2048 + i0) = oh;
                *(u16x4*)(Otl + (long)j*2048 + i0) = ol;
            }
        }
    }
}

// =====================================================================
// Combine v2: out = sum_jc sum_d E[n,d]*(A_jc W[d]_jc) + bias.
// L2-traffic fix: each wave owns ONE 16-o stripe over MI row-frags
// (gate MI=8 -> 128 rows, upd MI=4 -> 64 rows). No wave-pair weight
// duplication; W-frag reuse per load = MI (was 2). B demand drops
// ~273 -> ~40-80 B/cyc/CU (< L2 ~56 supply for gate) => MFMA-bound.
// W prefetch: 2 reg slots, distance 2, continuous across jc (10 even
// => d-parity == t-parity). A-frags held in regs across the d-loop.
// =====================================================================
template<int MI, int OFULL, int OHALFS, int ACT>
__global__ __launch_bounds__(256, 2) void k_combine(
    const float* __restrict__ G1r, const float* __restrict__ G2r,
    const float* __restrict__ x, const float* __restrict__ second,
    const u16* __restrict__ Wh, const u16* __restrict__ Wl,
    const float* __restrict__ bias, const float* __restrict__ E,
    float* __restrict__ out)
{
    constexpr int ROWS = MI*16;
    constexpr int RSH  = (ROWS == 128) ? 7 : 6;
    constexpr int NCH  = (ROWS*4)/256;           // staging chunks per thread
    __shared__ u16 Ash[ROWS*40], Asl[ROWS*40];
    __shared__ float Et[10*ROWS];

    const int tid = threadIdx.x, bid = blockIdx.x;
    const int rt = (OHALFS == 2) ? (bid & 255) : bid;   // row-tile
    const int oh = (OHALFS == 2) ? (bid >> 8) : 0;      // o-half
    const long row0 = (long)rt * ROWS;                  // global row (b*2048+n)
    const int b  = (int)(row0 >> 11);
    const int n0 = (int)(row0 & 2047);
    const int w = tid >> 6, lane = tid & 63;
    const int lr = lane & 15, lk = lane >> 4;
    const int wo = oh*64 + w*16;                        // this wave's o-stripe

    // E^T window: Et[d][r] = E[n0+r][d]
    for (int i = tid; i < 10*ROWS; i += 256)
        Et[i] = E[(n0 + (i & (ROWS-1)))*10 + (i >> RSH)];

    const f32x4 Z4 = {0.f, 0.f, 0.f, 0.f};
    f32x4 acc[MI];
    #pragma unroll
    for (int mi = 0; mi < MI; mi++) acc[mi] = Z4;

    // W fragment address for this wave: tile layout [o][32 k], lane reads
    // (o = wo+lr, k = lk*8..lk*8+7) -> 64 lanes cover contiguous 1 KiB.
    const int laneoff = (wo + lr)*32 + lk*8;

    // prefetch tiles t=0,1 (slot = t&1)
    s16x8 pbh[2], pbl[2];
    pbh[0] = *(const s16x8*)(Wh + laneoff);
    pbl[0] = *(const s16x8*)(Wl + laneoff);
    pbh[1] = *(const s16x8*)(Wh + (long)OFULL*32 + laneoff);
    pbl[1] = *(const s16x8*)(Wl + (long)OFULL*32 + laneoff);

    for (int jc = 0; jc < 12; jc++){
        __syncthreads();                     // prior jc's A-frag reads done
        // ---- stage A (ROWS x 32, fp32 -> hi/lo bf16) ----
        {
            const float* src; int stride;
            if (jc < 4){
                int col0 = jc*32;
                src = (col0 < 64) ? (x + row0*64 + col0)
                                  : (second + row0*64 + (col0 - 64));
                stride = 64;
            } else if (jc < 8){
                src = G1r + row0*128 + (jc-4)*32; stride = 128;
            } else {
                src = G2r + row0*128 + (jc-8)*32; stride = 128;
            }
            #pragma unroll
            for (int ch = 0; ch < NCH; ch++){
                int idx = tid + ch*256;
                int row = idx >> 2, c8 = (idx & 3) << 3;
                f32x4 s0 = *(const f32x4*)(src + (long)row*stride + c8);
                f32x4 s1 = *(const f32x4*)(src + (long)row*stride + c8 + 4);
                s16x8 vh, vl;
                #pragma unroll
                for (int t = 0; t < 4; t++){
                    u16 h,l; split_bf(s0[t], h, l); vh[t]=(short)h; vl[t]=(short)l;
                }
                #pragma unroll
                for (int t = 0; t < 4; t++){
                    u16 h,l; split_bf(s1[t], h, l); vh[4+t]=(short)h; vl[4+t]=(short)l;
                }
                *(s16x8*)&Ash[row*40 + c8] = vh;
                *(s16x8*)&Asl[row*40 + c8] = vl;
            }
        }
        __syncthreads();

        s16x8 ah[MI], al[MI];
        #pragma unroll
        for (int mi = 0; mi < MI; mi++){
            ah[mi] = *(const s16x8*)&Ash[(mi*16 + lr)*40 + lk*8];
            al[mi] = *(const s16x8*)&Asl[(mi*16 + lr)*40 + lk*8];
        }

        #pragma unroll
        for (int d = 0; d < 10; d++){
            const int cur = d & 1;
            f32x4 Cd[MI];
            #pragma unroll
            for (int mi = 0; mi < MI; mi++)
                Cd[mi] = __builtin_amdgcn_mfma_f32_16x16x32_bf16(ah[mi], pbh[cur], Z4, 0,0,0);
            #pragma unroll
            for (int mi = 0; mi < MI; mi++)
                Cd[mi] = __builtin_amdgcn_mfma_f32_16x16x32_bf16(al[mi], pbh[cur], Cd[mi], 0,0,0);
            #pragma unroll
            for (int mi = 0; mi < MI; mi++)
                Cd[mi] = __builtin_amdgcn_mfma_f32_16x16x32_bf16(ah[mi], pbl[cur], Cd[mi], 0,0,0);
            // prefetch tile t+2 into the slot just consumed
            int tn = jc*10 + d + 2;
            if (tn < 120){
                const long tb = (long)tn*OFULL*32 + laneoff;
                pbh[cur] = *(const s16x8*)(Wh + tb);
                pbl[cur] = *(const s16x8*)(Wl + tb);
            }
            #pragma unroll
            for (int mi = 0; mi < MI; mi++){
                f32x4 e4 = *(const f32x4*)&Et[d*ROWS + mi*16 + lk*4];
                acc[mi] += e4 * Cd[mi];
            }
        }
    }

    #pragma unroll
    for (int mi = 0; mi < MI; mi++){
        int nrow = n0 + mi*16 + lk*4;
        int o = wo + lr;
        #pragma unroll
        for (int r = 0; r < 4; r++){
            float v = acc[mi][r] + bias[(long)(nrow + r)*OFULL + o];
            v = (ACT == 0) ? (1.f/(1.f + __expf(-v))) : tanhf(v);
            out[((long)b*2048 + nrow + r)*OFULL + o] = v;
        }
    }
}

// =====================================================================
// K6: zr = Zg @ lin_w^T + lin_b
// =====================================================================
__global__ __launch_bounds__(256) void k_lin(const float* __restrict__ Zg,
                                             const float* __restrict__ lw,
                                             const float* __restrict__ lb,
                                             float* __restrict__ zr)
{
    __shared__ float wl[64*132];
    const int tid = threadIdx.x;
    for (int i = tid; i < 8192; i += 256) wl[(i >> 7)*132 + (i & 127)] = lw[i];
    __syncthreads();
    int gid = blockIdx.x*256 + tid;
    int row = gid >> 3, og = (gid & 7) << 3;
    float a[8];
    #pragma unroll
    for (int t = 0; t < 8; t++) a[t] = lb[og + t];
    const float* zrow = Zg + (long)row*128;
    #pragma unroll
    for (int jc = 0; jc < 8; jc++){
        f32x4 x0 = *(const f32x4*)(zrow + jc*16);
        f32x4 x1 = *(const f32x4*)(zrow + jc*16 + 4);
        f32x4 x2 = *(const f32x4*)(zrow + jc*16 + 8);
        f32x4 x3 = *(const f32x4*)(zrow + jc*16 + 12);
        #pragma unroll
        for (int t = 0; t < 8; t++){
            const float* wr = &wl[(og + t)*132 + jc*16];
            f32x4 w0 = *(const f32x4*)(wr);
            f32x4 w1 = *(const f32x4*)(wr + 4);
            f32x4 w2 = *(const f32x4*)(wr + 8);
            f32x4 w3 = *(const f32x4*)(wr + 12);
            f32x4 p = x0*w0 + x1*w1 + x2*w2 + x3*w3;
            a[t] += p[0] + p[1] + p[2] + p[3];
        }
    }
    #pragma unroll
    for (int t = 0; t < 8; t++) zr[(long)row*64 + og + t] = a[t];
}

// =====================================================================
// K7: pack candidate^T [colG][m] hi/lo from x | zr
// =====================================================================
__global__ __launch_bounds__(256) void k_packu(const float* __restrict__ x,
                                               const float* __restrict__ zr,
                                               u16* __restrict__ Th, u16* __restrict__ Tl)
{
    int idx = blockIdx.x*256 + threadIdx.x;
    int colG = idx >> 11, m = idx & 2047;
    int b = colG >> 7, c = colG & 127;
    float v = (c < 64) ? x[((long)(b*2048) + m)*64 + c]
                       : zr[((long)(b*2048) + m)*64 + c - 64];
    u16 h, l; split_bf(v, h, l);
    Th[idx] = h; Tl[idx] = l;
}

// =====================================================================
extern "C" void kernel_launch(void* const* d_in, const int* in_sizes, int n_in,
                              void* d_out, int out_size, void* d_ws, size_t ws_size,
                              hipStream_t stream)
{
    const float* x   = (const float*)d_in[0];
    const float* st  = (const float*)d_in[1];
    const float* E   = (const float*)d_in[2];
    const float* gwp = (const float*)d_in[3];
    const float* gbp = (const float*)d_in[4];
    const float* uwp = (const float*)d_in[5];
    const float* ubp = (const float*)d_in[6];
    const float* lw  = (const float*)d_in[7];
    const float* lb  = (const float*)d_in[8];
    float* out = (float*)d_out;
    char* ws = (char*)d_ws;

    const size_t MB8 = 8388608;
    u16*   Sh   = (u16*)(ws);
    u16*   Sl   = (u16*)(ws + 1*MB8);
    u16*   Xth  = (u16*)(ws + 2*MB8);         // gate X^T, repacked for candidate
    u16*   Xtl  = (u16*)(ws + 3*MB8);
    u16*   G1th = (u16*)(ws + 4*MB8);
    u16*   G1tl = (u16*)(ws + 5*MB8);
    float* G1row= (float*)(ws + 6*MB8);       // 16 MB
    float* G2row= (float*)(ws + 8*MB8);       // 16 MB
    float* Zg   = (float*)(ws + 10*MB8);      // 16 MB dedicated (no aliasing)
    float* zr   = (float*)(ws + 12*MB8);      // 8 MB
    char*  p    = ws + 13*MB8;
    u16* wgh = (u16*)p;            p += 983040;
    u16* wgl = (u16*)p;            p += 983040;
    u16* wuh = (u16*)p;            p += 491520;
    u16* wul = (u16*)p;            p += 491520;
    float* bg = (float*)p;         p += 1048576;
    float* bu = (float*)p;         p += 524288;

    k_supports<<<dim3(2048), dim3(256), 0, stream>>>(E, Sh, Sl);
    k_prep<<<dim3(20800), dim3(256), 0, stream>>>(E, gwp, gbp, uwp, ubp, x, st,
                                                  wgh, wgl, wuh, wul, bg, bu, Xth, Xtl);
    // gate diffusion (512 blocks: 64x128 tiles)
    k_gemm<0><<<dim3(512), dim3(256), 0, stream>>>(Sh, Sl, Xth, Xtl,
                                                   G1th, G1tl, G1row,
                                                   (const u16*)nullptr, (const u16*)nullptr);
    k_gemm<1><<<dim3(512), dim3(256), 0, stream>>>(Sh, Sl, G1th, G1tl,
                                                   (u16*)nullptr, (u16*)nullptr, G2row,
                                                   Xth, Xtl);
    // gate combine -> Zg (sigmoid): 256 row-tiles (128 rows) x 2 o-halves
    k_combine<8,128,2,0><<<dim3(512), dim3(256), 0, stream>>>(G1row, G2row, x, st,
                                                              wgh, wgl, bg, E, Zg);
    k_lin<<<dim3(1024), dim3(256), 0, stream>>>(Zg, lw, lb, zr);
    k_packu<<<dim3(16384), dim3(256), 0, stream>>>(x, zr, Xth, Xtl);
    // update diffusion
    k_gemm<0><<<dim3(512), dim3(256), 0, stream>>>(Sh, Sl, Xth, Xtl,
                                                   G1th, G1tl, G1row,
                                                   (const u16*)nullptr, (const u16*)nullptr);
    k_gemm<1><<<dim3(512), dim3(256), 0, stream>>>(Sh, Sl, G1th, G1tl,
                                                   (u16*)nullptr, (u16*)nullptr, G2row,
                                                   Xth, Xtl);
    // update combine -> out (tanh): 512 row-tiles (64 rows), full 64-o
    k_combine<4,64,1,1><<<dim3(512), dim3(256), 0, stream>>>(G1row, G2row, x, zr,
                                                             wuh, wul, bu, E, out);
}

// Round 2
// 626.186 us; speedup vs baseline: 2.9909x; 2.9909x over previous
//
#include <hip/hip_runtime.h>

typedef unsigned short u16;
typedef short s16x8 __attribute__((ext_vector_type(8)));
typedef float f32x4 __attribute__((ext_vector_type(4)));
typedef u16 u16x4 __attribute__((ext_vector_type(4)));

#define DEV static __device__ __forceinline__

// ---------- bf16 helpers (RTNE) ----------
DEV u16 f2bf(float x){
    union { float f; unsigned u; } v; v.f = x;
    unsigned r = v.u + 0x7FFFu + ((v.u >> 16) & 1u);
    return (u16)(r >> 16);
}
DEV float bf2f(u16 h){
    union { unsigned u; float f; } v; v.u = ((unsigned)h) << 16; return v.f;
}
DEV void split_bf(float x, u16& h, u16& l){
    h = f2bf(x);
    l = f2bf(x - bf2f(h));
}

// =====================================================================
// K1: supports = softmax(relu(E E^T)) row-wise -> hi/lo bf16 pair
// =====================================================================
__global__ __launch_bounds__(256) void k_supports(const float* __restrict__ E,
                                                  u16* __restrict__ Sh, u16* __restrict__ Sl)
{
    const int n = blockIdx.x, tid = threadIdx.x;
    const int w = tid >> 6, lane = tid & 63;
    __shared__ float red[8];

    float en[10];
    #pragma unroll
    for (int d = 0; d < 10; d++) en[d] = E[n*10 + d];

    float v[8];
    #pragma unroll
    for (int i = 0; i < 8; i++){
        int m = tid + i*256;
        const float* em = E + m*10;
        float s = 0.f;
        #pragma unroll
        for (int d = 0; d < 10; d++) s += en[d]*em[d];
        v[i] = fmaxf(s, 0.f);
    }
    float mx = v[0];
    #pragma unroll
    for (int i = 1; i < 8; i++) mx = fmaxf(mx, v[i]);
    #pragma unroll
    for (int off = 32; off > 0; off >>= 1) mx = fmaxf(mx, __shfl_xor(mx, off));
    if (lane == 0) red[w] = mx;
    __syncthreads();
    mx = fmaxf(fmaxf(red[0], red[1]), fmaxf(red[2], red[3]));
    __syncthreads();

    float sum = 0.f;
    #pragma unroll
    for (int i = 0; i < 8; i++){ v[i] = __expf(v[i] - mx); sum += v[i]; }
    #pragma unroll
    for (int off = 32; off > 0; off >>= 1) sum += __shfl_xor(sum, off);
    if (lane == 0) red[4 + w] = sum;
    __syncthreads();
    sum = red[4] + red[5] + red[6] + red[7];
    float inv = 1.f / sum;

    #pragma unroll
    for (int i = 0; i < 8; i++){
        float p = v[i] * inv;
        u16 h, l; split_bf(p, h, l);
        int m = tid + i*256;
        Sh[n*2048 + m] = h;
        Sl[n*2048 + m] = l;
    }
}

// =====================================================================
// K2: prep — weight pools -> [jc][d][o][k] hi/lo (per-(jc,d) tile is a
//     CONTIGUOUS block), biases E@bpool, X_gate^T pack.
// =====================================================================
__global__ __launch_bounds__(256) void k_prep(const float* __restrict__ E,
    const float* __restrict__ gwp, const float* __restrict__ gbp,
    const float* __restrict__ uwp, const float* __restrict__ ubp,
    const float* __restrict__ x,   const float* __restrict__ state,
    u16* __restrict__ wgh, u16* __restrict__ wgl,
    u16* __restrict__ wuh, u16* __restrict__ wul,
    float* __restrict__ bg, float* __restrict__ bu,
    u16* __restrict__ xth, u16* __restrict__ xtl)
{
    long idx = (long)blockIdx.x*256 + threadIdx.x;
    if (idx < 491520){                               // gate w -> [jc][d][128 o][32 k]
        int kk = (int)(idx & 31);
        int o  = (int)((idx >> 5) & 127);
        int r2 = (int)(idx >> 12);                   // 0..119
        int d = r2 % 10, jc = r2 / 10;
        int j = jc*32 + kk;                          // 0..383
        int k = j >> 7, i = j & 127;
        float v = gwp[(((d*3 + k)*128) + i)*128 + o];
        u16 h,l; split_bf(v,h,l); wgh[idx]=h; wgl[idx]=l;
    } else if (idx < 737280){                        // upd w -> [jc][d][64 o][32 k]
        long t = idx - 491520;
        int kk = (int)(t & 31);
        int o  = (int)((t >> 5) & 63);
        int r2 = (int)(t >> 11);                     // 0..119
        int d = r2 % 10, jc = r2 / 10;
        int j = jc*32 + kk;
        int k = j >> 7, i = j & 127;
        float v = uwp[(((d*3 + k)*128) + i)*64 + o];
        u16 h,l; split_bf(v,h,l); wuh[t]=h; wul[t]=l;
    } else if (idx < 999424){                        // bias_g [2048][128]
        long t = idx - 737280; int n = (int)(t >> 7), o = (int)(t & 127);
        float s = 0.f;
        #pragma unroll
        for (int d = 0; d < 10; d++) s += E[n*10+d]*gbp[d*128+o];
        bg[t] = s;
    } else if (idx < 1130496){                       // bias_u [2048][64]
        long t = idx - 999424; int n = (int)(t >> 6), o = (int)(t & 63);
        float s = 0.f;
        #pragma unroll
        for (int d = 0; d < 10; d++) s += E[n*10+d]*ubp[d*64+o];
        bu[t] = s;
    } else if (idx < 5324800){                       // X_gate^T pack
        long t = idx - 1130496;
        int colG = (int)(t >> 11), m = (int)(t & 2047);
        int b = colG >> 7, c = colG & 127;
        float v = (c < 64) ? x[((long)(b*2048)+m)*64 + c]
                           : state[((long)(b*2048)+m)*64 + c - 64];
        u16 h,l; split_bf(v,h,l); xth[t]=h; xtl[t]=l;
    }
}

// =====================================================================
// Diffusion GEMM  C[i][j] = sum_k A[i][k] * Bt[j][k], 3-term split MFMA.
// 64x128 tile -> 512 blocks = 2 blocks/CU.
// EPI=0: store t-layout hi/lo + row-major f32. EPI=1: 2*acc-X, row f32.
// =====================================================================
template<int EPI>
__global__ __launch_bounds__(256) void k_gemm(
    const u16* __restrict__ Ah, const u16* __restrict__ Al,
    const u16* __restrict__ Bh, const u16* __restrict__ Bl,
    u16* __restrict__ Oth, u16* __restrict__ Otl, float* __restrict__ Orow,
    const u16* __restrict__ Xh, const u16* __restrict__ Xl)
{
    __shared__ u16 AsH[64*40], AsL[64*40], BsH[128*40], BsL[128*40];
    const int tid = threadIdx.x;
    const int bm = (blockIdx.x & 31) << 6;   // 32 row-tiles of 64 (node rows)
    const int bn = (blockIdx.x >> 5) << 7;   // 16 col-tiles of 128 (colG)
    const int w = tid >> 6, lane = tid & 63;
    const int wn = w << 5;                   // 32 cols per wave
    const int lr = lane & 15, lk = lane >> 4;

    const int ar = tid >> 2, ac = (tid & 3) << 3;    // staging: 64 rows x 32 cols
    const long gA  = (long)(bm + ar)*2048 + ac;
    const long gB0 = (long)(bn + ar)*2048 + ac;
    const long gB1 = (long)(bn + ar + 64)*2048 + ac;
    const int lA  = ar*40 + ac;
    const int lB0 = ar*40 + ac, lB1 = (ar + 64)*40 + ac;

    f32x4 acc[4][2];
    const f32x4 Z4 = {0.f, 0.f, 0.f, 0.f};
    #pragma unroll
    for (int i = 0; i < 4; i++)
        #pragma unroll
        for (int j = 0; j < 2; j++) acc[i][j] = Z4;

    s16x8 rah  = *(const s16x8*)(Ah + gA);
    s16x8 ral  = *(const s16x8*)(Al + gA);
    s16x8 rbh0 = *(const s16x8*)(Bh + gB0), rbh1 = *(const s16x8*)(Bh + gB1);
    s16x8 rbl0 = *(const s16x8*)(Bl + gB0), rbl1 = *(const s16x8*)(Bl + gB1);

    for (int k0 = 0; k0 < 2048; k0 += 32){
        __syncthreads();
        *(s16x8*)&AsH[lA]  = rah;  *(s16x8*)&AsL[lA]  = ral;
        *(s16x8*)&BsH[lB0] = rbh0; *(s16x8*)&BsH[lB1] = rbh1;
        *(s16x8*)&BsL[lB0] = rbl0; *(s16x8*)&BsL[lB1] = rbl1;
        __syncthreads();
        if (k0 + 32 < 2048){
            long ka = k0 + 32;
            rah  = *(const s16x8*)(Ah + gA + ka);
            ral  = *(const s16x8*)(Al + gA + ka);
            rbh0 = *(const s16x8*)(Bh + gB0 + ka); rbh1 = *(const s16x8*)(Bh + gB1 + ka);
            rbl0 = *(const s16x8*)(Bl + gB0 + ka); rbl1 = *(const s16x8*)(Bl + gB1 + ka);
        }
        #pragma unroll
        for (int s = 0; s < 3; s++){
            const u16* Ap = (s == 1) ? AsL : AsH;
            const u16* Bp = (s == 2) ? BsL : BsH;
            s16x8 af[4], bfv[2];
            #pragma unroll
            for (int mi = 0; mi < 4; mi++)
                af[mi] = *(const s16x8*)&Ap[(mi*16 + lr)*40 + lk*8];
            #pragma unroll
            for (int ni = 0; ni < 2; ni++)
                bfv[ni] = *(const s16x8*)&Bp[(wn + ni*16 + lr)*40 + lk*8];
            #pragma unroll
            for (int mi = 0; mi < 4; mi++)
                #pragma unroll
                for (int ni = 0; ni < 2; ni++)
                    acc[mi][ni] = __builtin_amdgcn_mfma_f32_16x16x32_bf16(
                        af[mi], bfv[ni], acc[mi][ni], 0, 0, 0);
        }
    }

    #pragma unroll
    for (int mi = 0; mi < 4; mi++){
        #pragma unroll
        for (int ni = 0; ni < 2; ni++){
            int i0 = bm + mi*16 + lk*4;          // node (4 consecutive)
            int j  = bn + wn + ni*16 + lr;       // colG
            f32x4 v = acc[mi][ni];
            if constexpr (EPI){
                u16x4 xh = *(const u16x4*)(Xh + (long)j*2048 + i0);
                u16x4 xl = *(const u16x4*)(Xl + (long)j*2048 + i0);
                #pragma unroll
                for (int r = 0; r < 4; r++)
                    v[r] = 2.f*v[r] - (bf2f(xh[r]) + bf2f(xl[r]));
            }
            int bb = j >> 7, cc = j & 127;
            float* rp = Orow + ((long)bb*2048 + i0)*128 + cc;
            #pragma unroll
            for (int r = 0; r < 4; r++) rp[(long)r*128] = v[r];
            if constexpr (!EPI){
                u16x4 oh, ol;
                #pragma unroll
                for (int r = 0; r < 4; r++){ u16 h,l; split_bf(v[r], h, l); oh[r]=h; ol[r]=l; }
                *(u16x4*)(Oth + (long)j*2048 + i0) = oh;
                *(u16x4*)(Otl + (long)j*2048 + i0) = ol;
            }
        }
    }
}

// =====================================================================
// Combine v3: out = sum_jc sum_d E[n,d]*(A_jc W[d]_jc) + bias.
// No-duplication wave->o-stripe decomposition (each wave owns ONE 16-o
// stripe over MI=4 row-frags). W-frag reuse per load = 4 (was 2) ->
// W L2 traffic halved vs v8 baseline. MI kept at 4: MI=8 needed ~164
// VGPR and spilled catastrophically under the 128 cap (round-1: 2.7 GB
// scratch writes/dispatch). Plain launch_bounds(256): never force the
// allocator under its natural allocation.
// Gate: 512 row-tiles x 2 o-halves = 1024 blocks. Upd: 512 blocks.
// =====================================================================
template<int OFULL, int OHALFS, int ACT>
__global__ __launch_bounds__(256) void k_combine(
    const float* __restrict__ G1r, const float* __restrict__ G2r,
    const float* __restrict__ x, const float* __restrict__ second,
    const u16* __restrict__ Wh, const u16* __restrict__ Wl,
    const float* __restrict__ bias, const float* __restrict__ E,
    float* __restrict__ out)
{
    constexpr int MI = 4;
    constexpr int ROWS = 64;
    constexpr int RT = 512;                      // row-tiles (32768/64)
    __shared__ u16 Ash[ROWS*40], Asl[ROWS*40];
    __shared__ float Et[10*ROWS];

    const int tid = threadIdx.x, bid = blockIdx.x;
    const int rt = (OHALFS == 2) ? (bid & (RT-1)) : bid;   // row-tile
    const int oh = (OHALFS == 2) ? (bid >> 9)    : 0;      // o-half
    const long row0 = (long)rt * ROWS;                     // global row (b*2048+n)
    const int b  = (int)(row0 >> 11);
    const int n0 = (int)(row0 & 2047);
    const int w = tid >> 6, lane = tid & 63;
    const int lr = lane & 15, lk = lane >> 4;
    const int wo = oh*64 + w*16;                           // this wave's o-stripe

    // E^T window: Et[d][r] = E[n0+r][d]
    for (int i = tid; i < 10*ROWS; i += 256)
        Et[i] = E[(n0 + (i & (ROWS-1)))*10 + (i >> 6)];

    const f32x4 Z4 = {0.f, 0.f, 0.f, 0.f};
    f32x4 acc[MI];
    #pragma unroll
    for (int mi = 0; mi < MI; mi++) acc[mi] = Z4;

    // W fragment address for this wave: tile layout [o][32 k], lane reads
    // (o = wo+lr, k = lk*8..lk*8+7) -> 64 lanes cover contiguous 1 KiB.
    const int laneoff = (wo + lr)*32 + lk*8;

    // prefetch tiles t=0,1 (slot = t&1)
    s16x8 pbh[2], pbl[2];
    pbh[0] = *(const s16x8*)(Wh + laneoff);
    pbl[0] = *(const s16x8*)(Wl + laneoff);
    pbh[1] = *(const s16x8*)(Wh + (long)OFULL*32 + laneoff);
    pbl[1] = *(const s16x8*)(Wl + (long)OFULL*32 + laneoff);

    for (int jc = 0; jc < 12; jc++){
        __syncthreads();                     // prior jc's A-frag reads done
        // ---- stage A (64 rows x 32 cols, fp32 -> hi/lo bf16) ----
        {
            const float* src; int stride;
            if (jc < 4){
                int col0 = jc*32;
                src = (col0 < 64) ? (x + row0*64 + col0)
                                  : (second + row0*64 + (col0 - 64));
                stride = 64;
            } else if (jc < 8){
                src = G1r + row0*128 + (jc-4)*32; stride = 128;
            } else {
                src = G2r + row0*128 + (jc-8)*32; stride = 128;
            }
            int row = tid >> 2, c8 = (tid & 3) << 3;
            f32x4 s0 = *(const f32x4*)(src + (long)row*stride + c8);
            f32x4 s1 = *(const f32x4*)(src + (long)row*stride + c8 + 4);
            s16x8 vh, vl;
            #pragma unroll
            for (int t = 0; t < 4; t++){
                u16 h,l; split_bf(s0[t], h, l); vh[t]=(short)h; vl[t]=(short)l;
            }
            #pragma unroll
            for (int t = 0; t < 4; t++){
                u16 h,l; split_bf(s1[t], h, l); vh[4+t]=(short)h; vl[4+t]=(short)l;
            }
            *(s16x8*)&Ash[row*40 + c8] = vh;
            *(s16x8*)&Asl[row*40 + c8] = vl;
        }
        __syncthreads();

        s16x8 ah[MI], al[MI];
        #pragma unroll
        for (int mi = 0; mi < MI; mi++){
            ah[mi] = *(const s16x8*)&Ash[(mi*16 + lr)*40 + lk*8];
            al[mi] = *(const s16x8*)&Asl[(mi*16 + lr)*40 + lk*8];
        }

        #pragma unroll
        for (int d = 0; d < 10; d++){
            const int cur = d & 1;
            f32x4 Cd[MI];
            #pragma unroll
            for (int mi = 0; mi < MI; mi++)
                Cd[mi] = __builtin_amdgcn_mfma_f32_16x16x32_bf16(ah[mi], pbh[cur], Z4, 0,0,0);
            #pragma unroll
            for (int mi = 0; mi < MI; mi++)
                Cd[mi] = __builtin_amdgcn_mfma_f32_16x16x32_bf16(al[mi], pbh[cur], Cd[mi], 0,0,0);
            #pragma unroll
            for (int mi = 0; mi < MI; mi++)
                Cd[mi] = __builtin_amdgcn_mfma_f32_16x16x32_bf16(ah[mi], pbl[cur], Cd[mi], 0,0,0);
            // prefetch tile t+2 into the slot just consumed
            int tn = jc*10 + d + 2;
            if (tn < 120){
                const long tb = (long)tn*OFULL*32 + laneoff;
                pbh[cur] = *(const s16x8*)(Wh + tb);
                pbl[cur] = *(const s16x8*)(Wl + tb);
            }
            #pragma unroll
            for (int mi = 0; mi < MI; mi++){
                f32x4 e4 = *(const f32x4*)&Et[d*ROWS + mi*16 + lk*4];
                acc[mi] += e4 * Cd[mi];
            }
        }
    }

    #pragma unroll
    for (int mi = 0; mi < MI; mi++){
        int nrow = n0 + mi*16 + lk*4;
        int o = wo + lr;
        #pragma unroll
        for (int r = 0; r < 4; r++){
            float v = acc[mi][r] + bias[(long)(nrow + r)*OFULL + o];
            v = (ACT == 0) ? (1.f/(1.f + __expf(-v))) : tanhf(v);
            out[((long)b*2048 + nrow + r)*OFULL + o] = v;
        }
    }
}

// =====================================================================
// K6: zr = Zg @ lin_w^T + lin_b
// =====================================================================
__global__ __launch_bounds__(256) void k_lin(const float* __restrict__ Zg,
                                             const float* __restrict__ lw,
                                             const float* __restrict__ lb,
                                             float* __restrict__ zr)
{
    __shared__ float wl[64*132];
    const int tid = threadIdx.x;
    for (int i = tid; i < 8192; i += 256) wl[(i >> 7)*132 + (i & 127)] = lw[i];
    __syncthreads();
    int gid = blockIdx.x*256 + tid;
    int row = gid >> 3, og = (gid & 7) << 3;
    float a[8];
    #pragma unroll
    for (int t = 0; t < 8; t++) a[t] = lb[og + t];
    const float* zrow = Zg + (long)row*128;
    #pragma unroll
    for (int jc = 0; jc < 8; jc++){
        f32x4 x0 = *(const f32x4*)(zrow + jc*16);
        f32x4 x1 = *(const f32x4*)(zrow + jc*16 + 4);
        f32x4 x2 = *(const f32x4*)(zrow + jc*16 + 8);
        f32x4 x3 = *(const f32x4*)(zrow + jc*16 + 12);
        #pragma unroll
        for (int t = 0; t < 8; t++){
            const float* wr = &wl[(og + t)*132 + jc*16];
            f32x4 w0 = *(const f32x4*)(wr);
            f32x4 w1 = *(const f32x4*)(wr + 4);
            f32x4 w2 = *(const f32x4*)(wr + 8);
            f32x4 w3 = *(const f32x4*)(wr + 12);
            f32x4 p = x0*w0 + x1*w1 + x2*w2 + x3*w3;
            a[t] += p[0] + p[1] + p[2] + p[3];
        }
    }
    #pragma unroll
    for (int t = 0; t < 8; t++) zr[(long)row*64 + og + t] = a[t];
}

// =====================================================================
// K7: pack candidate^T [colG][m] hi/lo from x | zr
// =====================================================================
__global__ __launch_bounds__(256) void k_packu(const float* __restrict__ x,
                                               const float* __restrict__ zr,
                                               u16* __restrict__ Th, u16* __restrict__ Tl)
{
    int idx = blockIdx.x*256 + threadIdx.x;
    int colG = idx >> 11, m = idx & 2047;
    int b = colG >> 7, c = colG & 127;
    float v = (c < 64) ? x[((long)(b*2048) + m)*64 + c]
                       : zr[((long)(b*2048) + m)*64 + c - 64];
    u16 h, l; split_bf(v, h, l);
    Th[idx] = h; Tl[idx] = l;
}

// =====================================================================
extern "C" void kernel_launch(void* const* d_in, const int* in_sizes, int n_in,
                              void* d_out, int out_size, void* d_ws, size_t ws_size,
                              hipStream_t stream)
{
    const float* x   = (const float*)d_in[0];
    const float* st  = (const float*)d_in[1];
    const float* E   = (const float*)d_in[2];
    const float* gwp = (const float*)d_in[3];
    const float* gbp = (const float*)d_in[4];
    const float* uwp = (const float*)d_in[5];
    const float* ubp = (const float*)d_in[6];
    const float* lw  = (const float*)d_in[7];
    const float* lb  = (const float*)d_in[8];
    float* out = (float*)d_out;
    char* ws = (char*)d_ws;

    const size_t MB8 = 8388608;
    u16*   Sh   = (u16*)(ws);
    u16*   Sl   = (u16*)(ws + 1*MB8);
    u16*   Xth  = (u16*)(ws + 2*MB8);         // gate X^T, repacked for candidate
    u16*   Xtl  = (u16*)(ws + 3*MB8);
    u16*   G1th = (u16*)(ws + 4*MB8);
    u16*   G1tl = (u16*)(ws + 5*MB8);
    float* G1row= (float*)(ws + 6*MB8);       // 16 MB
    float* G2row= (float*)(ws + 8*MB8);       // 16 MB
    float* Zg   = (float*)(ws + 10*MB8);      // 16 MB dedicated (no aliasing)
    float* zr   = (float*)(ws + 12*MB8);      // 8 MB
    char*  p    = ws + 13*MB8;
    u16* wgh = (u16*)p;            p += 983040;
    u16* wgl = (u16*)p;            p += 983040;
    u16* wuh = (u16*)p;            p += 491520;
    u16* wul = (u16*)p;            p += 491520;
    float* bg = (float*)p;         p += 1048576;
    float* bu = (float*)p;         p += 524288;

    k_supports<<<dim3(2048), dim3(256), 0, stream>>>(E, Sh, Sl);
    k_prep<<<dim3(20800), dim3(256), 0, stream>>>(E, gwp, gbp, uwp, ubp, x, st,
                                                  wgh, wgl, wuh, wul, bg, bu, Xth, Xtl);
    // gate diffusion (512 blocks: 64x128 tiles)
    k_gemm<0><<<dim3(512), dim3(256), 0, stream>>>(Sh, Sl, Xth, Xtl,
                                                   G1th, G1tl, G1row,
                                                   (const u16*)nullptr, (const u16*)nullptr);
    k_gemm<1><<<dim3(512), dim3(256), 0, stream>>>(Sh, Sl, G1th, G1tl,
                                                   (u16*)nullptr, (u16*)nullptr, G2row,
                                                   Xth, Xtl);
    // gate combine -> Zg (sigmoid): 512 row-tiles x 2 o-halves = 1024 blocks
    k_combine<128,2,0><<<dim3(1024), dim3(256), 0, stream>>>(G1row, G2row, x, st,
                                                             wgh, wgl, bg, E, Zg);
    k_lin<<<dim3(1024), dim3(256), 0, stream>>>(Zg, lw, lb, zr);
    k_packu<<<dim3(16384), dim3(256), 0, stream>>>(x, zr, Xth, Xtl);
    // update diffusion
    k_gemm<0><<<dim3(512), dim3(256), 0, stream>>>(Sh, Sl, Xth, Xtl,
                                                   G1th, G1tl, G1row,
                                                   (const u16*)nullptr, (const u16*)nullptr);
    k_gemm<1><<<dim3(512), dim3(256), 0, stream>>>(Sh, Sl, G1th, G1tl,
                                                   (u16*)nullptr, (u16*)nullptr, G2row,
                                                   Xth, Xtl);
    // update combine -> out (tanh): 512 blocks, full 64-o
    k_combine<64,1,1><<<dim3(512), dim3(256), 0, stream>>>(G1row, G2row, x, zr,
                                                           wuh, wul, bu, E, out);
}

// Round 3
// 455.966 us; speedup vs baseline: 4.1074x; 1.3733x over previous
//
#include <hip/hip_runtime.h>

typedef unsigned short u16;
typedef short s16x8 __attribute__((ext_vector_type(8)));
typedef _Float16 h16x8 __attribute__((ext_vector_type(8)));
typedef float f32x4 __attribute__((ext_vector_type(4)));
typedef u16 u16x4 __attribute__((ext_vector_type(4)));

#define DEV static __device__ __forceinline__

// ---------- f16 limb helpers (RTNE via v_cvt_f16_f32) ----------
DEV u16 f2h(float x){ union { _Float16 h; u16 u; } v; v.h = (_Float16)x; return v.u; }
DEV float h2f(u16 u){ union { u16 u; _Float16 h; } v; v.u = u; return (float)v.h; }
DEV void split_h(float x, u16& h, u16& l){
    h = f2h(x);
    l = f2h(x - h2f(h));
}
DEV h16x8 H8(s16x8 v){ union { s16x8 s; h16x8 h; } u; u.s = v; return u.h; }
DEV f32x4 mfma16(s16x8 a, s16x8 b, f32x4 c){
    return __builtin_amdgcn_mfma_f32_16x16x32_f16(H8(a), H8(b), c, 0, 0, 0);
}

// =====================================================================
// K1: supports = softmax(relu(E E^T)) row-wise -> hi/lo f16 limb pair
// (S is the split operand: computed once, used as A in all 4 gemms)
// =====================================================================
__global__ __launch_bounds__(256) void k_supports(const float* __restrict__ E,
                                                  u16* __restrict__ Sh, u16* __restrict__ Sl)
{
    const int n = blockIdx.x, tid = threadIdx.x;
    const int w = tid >> 6, lane = tid & 63;
    __shared__ float red[8];

    float en[10];
    #pragma unroll
    for (int d = 0; d < 10; d++) en[d] = E[n*10 + d];

    float v[8];
    #pragma unroll
    for (int i = 0; i < 8; i++){
        int m = tid + i*256;
        const float* em = E + m*10;
        float s = 0.f;
        #pragma unroll
        for (int d = 0; d < 10; d++) s += en[d]*em[d];
        v[i] = fmaxf(s, 0.f);
    }
    float mx = v[0];
    #pragma unroll
    for (int i = 1; i < 8; i++) mx = fmaxf(mx, v[i]);
    #pragma unroll
    for (int off = 32; off > 0; off >>= 1) mx = fmaxf(mx, __shfl_xor(mx, off));
    if (lane == 0) red[w] = mx;
    __syncthreads();
    mx = fmaxf(fmaxf(red[0], red[1]), fmaxf(red[2], red[3]));
    __syncthreads();

    float sum = 0.f;
    #pragma unroll
    for (int i = 0; i < 8; i++){ v[i] = __expf(v[i] - mx); sum += v[i]; }
    #pragma unroll
    for (int off = 32; off > 0; off >>= 1) sum += __shfl_xor(sum, off);
    if (lane == 0) red[4 + w] = sum;
    __syncthreads();
    sum = red[4] + red[5] + red[6] + red[7];
    float inv = 1.f / sum;

    #pragma unroll
    for (int i = 0; i < 8; i++){
        float p = v[i] * inv;
        u16 h, l; split_h(p, h, l);
        int m = tid + i*256;
        Sh[n*2048 + m] = h;
        Sl[n*2048 + m] = l;
    }
}

// =====================================================================
// K2: prep — weight pools -> [jc][d][o][k] SINGLE f16, biases E@bpool,
// X_gate^T pack (single f16). Index thresholds identical to bf16 version
// (same logical index space; only the stores changed).
// =====================================================================
__global__ __launch_bounds__(256) void k_prep(const float* __restrict__ E,
    const float* __restrict__ gwp, const float* __restrict__ gbp,
    const float* __restrict__ uwp, const float* __restrict__ ubp,
    const float* __restrict__ x,   const float* __restrict__ state,
    u16* __restrict__ wg, u16* __restrict__ wu,
    float* __restrict__ bg, float* __restrict__ bu,
    u16* __restrict__ xt)
{
    long idx = (long)blockIdx.x*256 + threadIdx.x;
    if (idx < 491520){                               // gate w -> [jc][d][128 o][32 k]
        int kk = (int)(idx & 31);
        int o  = (int)((idx >> 5) & 127);
        int r2 = (int)(idx >> 12);                   // 0..119
        int d = r2 % 10, jc = r2 / 10;
        int j = jc*32 + kk;                          // 0..383
        int k = j >> 7, i = j & 127;
        float v = gwp[(((d*3 + k)*128) + i)*128 + o];
        wg[idx] = f2h(v);
    } else if (idx < 737280){                        // upd w -> [jc][d][64 o][32 k]
        long t = idx - 491520;
        int kk = (int)(t & 31);
        int o  = (int)((t >> 5) & 63);
        int r2 = (int)(t >> 11);                     // 0..119
        int d = r2 % 10, jc = r2 / 10;
        int j = jc*32 + kk;
        int k = j >> 7, i = j & 127;
        float v = uwp[(((d*3 + k)*128) + i)*64 + o];
        wu[t] = f2h(v);
    } else if (idx < 999424){                        // bias_g [2048][128]
        long t = idx - 737280; int n = (int)(t >> 7), o = (int)(t & 127);
        float s = 0.f;
        #pragma unroll
        for (int d = 0; d < 10; d++) s += E[n*10+d]*gbp[d*128+o];
        bg[t] = s;
    } else if (idx < 1130496){                       // bias_u [2048][64]
        long t = idx - 999424; int n = (int)(t >> 6), o = (int)(t & 63);
        float s = 0.f;
        #pragma unroll
        for (int d = 0; d < 10; d++) s += E[n*10+d]*ubp[d*64+o];
        bu[t] = s;
    } else if (idx < 5324800){                       // X_gate^T pack (single f16)
        long t = idx - 1130496;
        int colG = (int)(t >> 11), m = (int)(t & 2047);
        int b = colG >> 7, c = colG & 127;
        float v = (c < 64) ? x[((long)(b*2048)+m)*64 + c]
                           : state[((long)(b*2048)+m)*64 + c - 64];
        xt[t] = f2h(v);
    }
}

// =====================================================================
// Diffusion GEMM  C[i][j] = sum_k A[i][k] * Bt[j][k].
// f16 2-limb: A = S hi/lo (split side), B = X single f16.
// MFMA per kstep: 16 (was 24 with bf16 3-limb); ds_read 10 (was 18).
// EPI=0: store t-layout single f16 + row-major f32. EPI=1: 2*acc-X.
// =====================================================================
template<int EPI>
__global__ __launch_bounds__(256) void k_gemm(
    const u16* __restrict__ Ah, const u16* __restrict__ Al,
    const u16* __restrict__ Bt,
    u16* __restrict__ Ot, float* __restrict__ Orow,
    const u16* __restrict__ Xt)
{
    __shared__ u16 AsH[64*40], AsL[64*40], Bs[128*40];
    const int tid = threadIdx.x;
    const int bm = (blockIdx.x & 31) << 6;   // 32 row-tiles of 64 (node rows)
    const int bn = (blockIdx.x >> 5) << 7;   // 16 col-tiles of 128 (colG)
    const int w = tid >> 6, lane = tid & 63;
    const int wn = w << 5;                   // 32 cols per wave
    const int lr = lane & 15, lk = lane >> 4;

    const int ar = tid >> 2, ac = (tid & 3) << 3;    // staging: 64 rows x 32 cols
    const long gA  = (long)(bm + ar)*2048 + ac;
    const long gB0 = (long)(bn + ar)*2048 + ac;
    const long gB1 = (long)(bn + ar + 64)*2048 + ac;
    const int lA  = ar*40 + ac;
    const int lB0 = ar*40 + ac, lB1 = (ar + 64)*40 + ac;

    f32x4 acc[4][2];
    const f32x4 Z4 = {0.f, 0.f, 0.f, 0.f};
    #pragma unroll
    for (int i = 0; i < 4; i++)
        #pragma unroll
        for (int j = 0; j < 2; j++) acc[i][j] = Z4;

    s16x8 rah = *(const s16x8*)(Ah + gA);
    s16x8 ral = *(const s16x8*)(Al + gA);
    s16x8 rb0 = *(const s16x8*)(Bt + gB0), rb1 = *(const s16x8*)(Bt + gB1);

    for (int k0 = 0; k0 < 2048; k0 += 32){
        __syncthreads();
        *(s16x8*)&AsH[lA] = rah;  *(s16x8*)&AsL[lA] = ral;
        *(s16x8*)&Bs[lB0] = rb0;  *(s16x8*)&Bs[lB1] = rb1;
        __syncthreads();
        if (k0 + 32 < 2048){
            long ka = k0 + 32;
            rah = *(const s16x8*)(Ah + gA + ka);
            ral = *(const s16x8*)(Al + gA + ka);
            rb0 = *(const s16x8*)(Bt + gB0 + ka);
            rb1 = *(const s16x8*)(Bt + gB1 + ka);
        }
        s16x8 bfv[2];
        #pragma unroll
        for (int ni = 0; ni < 2; ni++)
            bfv[ni] = *(const s16x8*)&Bs[(wn + ni*16 + lr)*40 + lk*8];
        #pragma unroll
        for (int s = 0; s < 2; s++){
            const u16* Ap = s ? AsL : AsH;
            s16x8 af[4];
            #pragma unroll
            for (int mi = 0; mi < 4; mi++)
                af[mi] = *(const s16x8*)&Ap[(mi*16 + lr)*40 + lk*8];
            #pragma unroll
            for (int mi = 0; mi < 4; mi++)
                #pragma unroll
                for (int ni = 0; ni < 2; ni++)
                    acc[mi][ni] = mfma16(af[mi], bfv[ni], acc[mi][ni]);
        }
    }

    #pragma unroll
    for (int mi = 0; mi < 4; mi++){
        #pragma unroll
        for (int ni = 0; ni < 2; ni++){
            int i0 = bm + mi*16 + lk*4;          // node (4 consecutive)
            int j  = bn + wn + ni*16 + lr;       // colG
            f32x4 v = acc[mi][ni];
            if constexpr (EPI){
                u16x4 xh = *(const u16x4*)(Xt + (long)j*2048 + i0);
                #pragma unroll
                for (int r = 0; r < 4; r++)
                    v[r] = 2.f*v[r] - h2f(xh[r]);
            }
            int bb = j >> 7, cc = j & 127;
            float* rp = Orow + ((long)bb*2048 + i0)*128 + cc;
            #pragma unroll
            for (int r = 0; r < 4; r++) rp[(long)r*128] = v[r];
            if constexpr (!EPI){
                u16x4 oh;
                #pragma unroll
                for (int r = 0; r < 4; r++) oh[r] = f2h(v[r]);
                *(u16x4*)(Ot + (long)j*2048 + i0) = oh;
            }
        }
    }
}

// =====================================================================
// Combine (round-0 proven structure, f16 2-limb): out = sum_jc sum_d
// E[n,d]*(A_jc W[d]_jc) + bias. 256 thr, (256,2), d fully unrolled,
// triple-buffer W prefetch dist 2, zero-C first MFMA.
// W is SINGLE f16 -> prefetch regs halved (48 vs 96), MFMA/d 16 vs 24,
// W L2 traffic halved. A staged as f16 hi/lo limbs in LDS.
// =====================================================================
template<int OFULL, int ACT>
__global__ __launch_bounds__(256, 2) void k_combine(
    const float* __restrict__ G1r, const float* __restrict__ G2r,
    const float* __restrict__ x, const float* __restrict__ second,
    const u16* __restrict__ W,
    const float* __restrict__ bias, const float* __restrict__ E,
    float* __restrict__ out)
{
    constexpr int NO = OFULL/32;                 // o-frags per wave (4 gate, 2 upd)
    __shared__ u16 Ash[64*40], Asl[64*40];
    __shared__ float Et[640];
    const int tid = threadIdx.x, bid = blockIdx.x;
    const int b = bid >> 5, n0 = (bid & 31) << 6;
    const int w = tid >> 6, lane = tid & 63;
    const int wm = (w & 1)*32, wo = (w >> 1)*(OFULL/2);
    const int lr = lane & 15, lk = lane >> 4;

    for (int i = tid; i < 640; i += 256)
        Et[i] = E[(n0 + (i & 63))*10 + (i >> 6)];

    const f32x4 Z4 = {0.f, 0.f, 0.f, 0.f};
    f32x4 acc[2][NO];
    #pragma unroll
    for (int mi = 0; mi < 2; mi++)
        #pragma unroll
        for (int oi = 0; oi < NO; oi++) acc[mi][oi] = Z4;

    const long rowbase = (long)b*2048 + n0;
    const int laneoff = (wo + lr)*32 + lk*8;     // u16 offset within tile

    s16x8 pbh[3][NO];

    for (int jc = 0; jc < 12; jc++){
        // preload W tiles d=0,1 (independent of A; overlap staging+barrier)
        {
            const long t0 = (long)(jc*10 + 0)*OFULL*32;
            const long t1 = (long)(jc*10 + 1)*OFULL*32;
            #pragma unroll
            for (int oi = 0; oi < NO; oi++){
                pbh[0][oi] = *(const s16x8*)(W + t0 + laneoff + oi*16*32);
                pbh[1][oi] = *(const s16x8*)(W + t1 + laneoff + oi*16*32);
            }
        }
        __syncthreads();   // prior jc's A-frag reads are long done
        // ---- stage A (one 16B chunk per thread, f16 hi/lo) ----
        {
            const float* src; int stride;
            if (jc < 4){
                int col0 = jc*32;
                src = (col0 < 64) ? (x + rowbase*64 + col0)
                                  : (second + rowbase*64 + (col0 - 64));
                stride = 64;
            } else if (jc < 8){
                src = G1r + rowbase*128 + (jc-4)*32; stride = 128;
            } else {
                src = G2r + rowbase*128 + (jc-8)*32; stride = 128;
            }
            int row = tid >> 2, c8 = (tid & 3)*8;
            f32x4 s0 = *(const f32x4*)(src + (long)row*stride + c8);
            f32x4 s1 = *(const f32x4*)(src + (long)row*stride + c8 + 4);
            s16x8 vh, vl;
            #pragma unroll
            for (int t = 0; t < 4; t++){
                u16 h,l; split_h(s0[t], h, l); vh[t]=(short)h; vl[t]=(short)l;
            }
            #pragma unroll
            for (int t = 0; t < 4; t++){
                u16 h,l; split_h(s1[t], h, l); vh[4+t]=(short)h; vl[4+t]=(short)l;
            }
            *(s16x8*)&Ash[row*40 + c8] = vh;
            *(s16x8*)&Asl[row*40 + c8] = vl;
        }
        __syncthreads();

        s16x8 ah[2], al[2];
        #pragma unroll
        for (int mi = 0; mi < 2; mi++){
            ah[mi] = *(const s16x8*)&Ash[(wm + mi*16 + lr)*40 + lk*8];
            al[mi] = *(const s16x8*)&Asl[(wm + mi*16 + lr)*40 + lk*8];
        }

        #pragma unroll
        for (int d = 0; d < 10; d++){
            const int cur = d % 3;               // compile-time after unroll
            if (d < 8){                          // prefetch d+2 into slot (d+2)%3
                const int nx = (d + 2) % 3;
                const long t2 = (long)(jc*10 + d + 2)*OFULL*32;
                #pragma unroll
                for (int oi = 0; oi < NO; oi++)
                    pbh[nx][oi] = *(const s16x8*)(W + t2 + laneoff + oi*16*32);
            }
            f32x4 Cd[2][NO];
            #pragma unroll
            for (int mi = 0; mi < 2; mi++)
                #pragma unroll
                for (int oi = 0; oi < NO; oi++)
                    Cd[mi][oi] = mfma16(ah[mi], pbh[cur][oi], Z4);
            #pragma unroll
            for (int mi = 0; mi < 2; mi++)
                #pragma unroll
                for (int oi = 0; oi < NO; oi++)
                    Cd[mi][oi] = mfma16(al[mi], pbh[cur][oi], Cd[mi][oi]);
            #pragma unroll
            for (int mi = 0; mi < 2; mi++){
                f32x4 e4 = *(const f32x4*)&Et[d*64 + wm + mi*16 + lk*4];
                #pragma unroll
                for (int oi = 0; oi < NO; oi++) acc[mi][oi] += e4 * Cd[mi][oi];
            }
        }
    }

    #pragma unroll
    for (int mi = 0; mi < 2; mi++){
        #pragma unroll
        for (int oi = 0; oi < NO; oi++){
            int mrow = n0 + wm + mi*16 + lk*4;
            int o = wo + oi*16 + lr;
            #pragma unroll
            for (int r = 0; r < 4; r++){
                float v = acc[mi][oi][r] + bias[(long)(mrow + r)*OFULL + o];
                v = (ACT == 0) ? (1.f/(1.f + __expf(-v))) : tanhf(v);
                out[((long)b*2048 + mrow + r)*OFULL + o] = v;
            }
        }
    }
}

// =====================================================================
// K6: zr = Zg @ lin_w^T + lin_b
// =====================================================================
__global__ __launch_bounds__(256) void k_lin(const float* __restrict__ Zg,
                                             const float* __restrict__ lw,
                                             const float* __restrict__ lb,
                                             float* __restrict__ zr)
{
    __shared__ float wl[64*132];
    const int tid = threadIdx.x;
    for (int i = tid; i < 8192; i += 256) wl[(i >> 7)*132 + (i & 127)] = lw[i];
    __syncthreads();
    int gid = blockIdx.x*256 + tid;
    int row = gid >> 3, og = (gid & 7) << 3;
    float a[8];
    #pragma unroll
    for (int t = 0; t < 8; t++) a[t] = lb[og + t];
    const float* zrow = Zg + (long)row*128;
    #pragma unroll
    for (int jc = 0; jc < 8; jc++){
        f32x4 x0 = *(const f32x4*)(zrow + jc*16);
        f32x4 x1 = *(const f32x4*)(zrow + jc*16 + 4);
        f32x4 x2 = *(const f32x4*)(zrow + jc*16 + 8);
        f32x4 x3 = *(const f32x4*)(zrow + jc*16 + 12);
        #pragma unroll
        for (int t = 0; t < 8; t++){
            const float* wr = &wl[(og + t)*132 + jc*16];
            f32x4 w0 = *(const f32x4*)(wr);
            f32x4 w1 = *(const f32x4*)(wr + 4);
            f32x4 w2 = *(const f32x4*)(wr + 8);
            f32x4 w3 = *(const f32x4*)(wr + 12);
            f32x4 p = x0*w0 + x1*w1 + x2*w2 + x3*w3;
            a[t] += p[0] + p[1] + p[2] + p[3];
        }
    }
    #pragma unroll
    for (int t = 0; t < 8; t++) zr[(long)row*64 + og + t] = a[t];
}

// =====================================================================
// K7: pack candidate^T [colG][m] single f16 from x | zr
// =====================================================================
__global__ __launch_bounds__(256) void k_packu(const float* __restrict__ x,
                                               const float* __restrict__ zr,
                                               u16* __restrict__ T)
{
    int idx = blockIdx.x*256 + threadIdx.x;
    int colG = idx >> 11, m = idx & 2047;
    int b = colG >> 7, c = colG & 127;
    float v = (c < 64) ? x[((long)(b*2048) + m)*64 + c]
                       : zr[((long)(b*2048) + m)*64 + c - 64];
    T[idx] = f2h(v);
}

// =====================================================================
extern "C" void kernel_launch(void* const* d_in, const int* in_sizes, int n_in,
                              void* d_out, int out_size, void* d_ws, size_t ws_size,
                              hipStream_t stream)
{
    const float* x   = (const float*)d_in[0];
    const float* st  = (const float*)d_in[1];
    const float* E   = (const float*)d_in[2];
    const float* gwp = (const float*)d_in[3];
    const float* gbp = (const float*)d_in[4];
    const float* uwp = (const float*)d_in[5];
    const float* ubp = (const float*)d_in[6];
    const float* lw  = (const float*)d_in[7];
    const float* lb  = (const float*)d_in[8];
    float* out = (float*)d_out;
    char* ws = (char*)d_ws;

    const size_t MB8 = 8388608;
    u16*   Sh   = (u16*)(ws);                 // 8 MB
    u16*   Sl   = (u16*)(ws + 1*MB8);         // 8 MB
    u16*   Xt   = (u16*)(ws + 2*MB8);         // 8 MB  (single f16 X^T / candidate^T)
    u16*   G1t  = (u16*)(ws + 3*MB8);         // 8 MB  (single f16 G1^T)
    float* G1row= (float*)(ws + 4*MB8);       // 16 MB
    float* G2row= (float*)(ws + 6*MB8);       // 16 MB
    float* Zg   = (float*)(ws + 8*MB8);       // 16 MB
    float* zr   = (float*)(ws + 10*MB8);      // 8 MB
    char*  p    = ws + 11*MB8;
    u16* wg = (u16*)p;             p += 983040;
    u16* wu = (u16*)p;             p += 491520;
    float* bg = (float*)p;         p += 1048576;
    float* bu = (float*)p;         p += 524288;

    k_supports<<<dim3(2048), dim3(256), 0, stream>>>(E, Sh, Sl);
    k_prep<<<dim3(20800), dim3(256), 0, stream>>>(E, gwp, gbp, uwp, ubp, x, st,
                                                  wg, wu, bg, bu, Xt);
    // gate diffusion
    k_gemm<0><<<dim3(512), dim3(256), 0, stream>>>(Sh, Sl, Xt, G1t, G1row,
                                                   (const u16*)nullptr);
    k_gemm<1><<<dim3(512), dim3(256), 0, stream>>>(Sh, Sl, G1t, (u16*)nullptr, G2row,
                                                   Xt);
    // gate combine -> Zg (sigmoid)
    k_combine<128,0><<<dim3(512), dim3(256), 0, stream>>>(G1row, G2row, x, st,
                                                          wg, bg, E, Zg);
    k_lin<<<dim3(1024), dim3(256), 0, stream>>>(Zg, lw, lb, zr);
    k_packu<<<dim3(16384), dim3(256), 0, stream>>>(x, zr, Xt);
    // update diffusion
    k_gemm<0><<<dim3(512), dim3(256), 0, stream>>>(Sh, Sl, Xt, G1t, G1row,
                                                   (const u16*)nullptr);
    k_gemm<1><<<dim3(512), dim3(256), 0, stream>>>(Sh, Sl, G1t, (u16*)nullptr, G2row,
                                                   Xt);
    // update combine -> out (tanh)
    k_combine<64,1><<<dim3(512), dim3(256), 0, stream>>>(G1row, G2row, x, zr,
                                                         wu, bu, E, out);
}

// Round 4
// 419.247 us; speedup vs baseline: 4.4671x; 1.0876x over previous
//
#include <hip/hip_runtime.h>

typedef unsigned short u16;
typedef short s16x8 __attribute__((ext_vector_type(8)));
typedef _Float16 h16x8 __attribute__((ext_vector_type(8)));
typedef float f32x4 __attribute__((ext_vector_type(4)));
typedef u16 u16x4 __attribute__((ext_vector_type(4)));

#define DEV static __device__ __forceinline__

// ---------- f16 limb helpers (RTNE via v_cvt_f16_f32) ----------
DEV u16 f2h(float x){ union { _Float16 h; u16 u; } v; v.h = (_Float16)x; return v.u; }
DEV float h2f(u16 u){ union { u16 u; _Float16 h; } v; v.u = u; return (float)v.h; }
DEV void split_h(float x, u16& h, u16& l){
    h = f2h(x);
    l = f2h(x - h2f(h));
}
DEV h16x8 H8(s16x8 v){ union { s16x8 s; h16x8 h; } u; u.s = v; return u.h; }
DEV f32x4 mfma16(s16x8 a, s16x8 b, f32x4 c){
    return __builtin_amdgcn_mfma_f32_16x16x32_f16(H8(a), H8(b), c, 0, 0, 0);
}

// ---------- t-layout chunk swizzle ----------
// Arrays [row][2048 m] store element (row, m) at column swz(row, m):
// bits 3-5 of m XOR'd with (row & 7). This makes global_load_lds (linear
// LDS dest) + ds_read_b128 frag reads exactly 2-way bank aliased (free).
// Invariant under k0 multiples of 64 (only bits 3-5 move).
DEV int swz(int r, int m){ return (m & ~0x38) | ((((m >> 3) ^ r) & 7) << 3); }

// global -> LDS direct (16B per lane; LDS dest = wave-uniform base + lane*16)
DEV void gll16(const u16* g, u16* l){
    __builtin_amdgcn_global_load_lds((const __attribute__((address_space(1))) void*)g,
                                     (__attribute__((address_space(3))) void*)l, 16, 0, 0);
}

// =====================================================================
// K1: supports = softmax(relu(E E^T)) row-wise -> hi/lo f16 limb pair,
// stored chunk-swizzled (row = n).
// =====================================================================
__global__ __launch_bounds__(256) void k_supports(const float* __restrict__ E,
                                                  u16* __restrict__ Sh, u16* __restrict__ Sl)
{
    const int n = blockIdx.x, tid = threadIdx.x;
    const int w = tid >> 6, lane = tid & 63;
    __shared__ float red[8];

    float en[10];
    #pragma unroll
    for (int d = 0; d < 10; d++) en[d] = E[n*10 + d];

    float v[8];
    #pragma unroll
    for (int i = 0; i < 8; i++){
        int m = tid + i*256;
        const float* em = E + m*10;
        float s = 0.f;
        #pragma unroll
        for (int d = 0; d < 10; d++) s += en[d]*em[d];
        v[i] = fmaxf(s, 0.f);
    }
    float mx = v[0];
    #pragma unroll
    for (int i = 1; i < 8; i++) mx = fmaxf(mx, v[i]);
    #pragma unroll
    for (int off = 32; off > 0; off >>= 1) mx = fmaxf(mx, __shfl_xor(mx, off));
    if (lane == 0) red[w] = mx;
    __syncthreads();
    mx = fmaxf(fmaxf(red[0], red[1]), fmaxf(red[2], red[3]));
    __syncthreads();

    float sum = 0.f;
    #pragma unroll
    for (int i = 0; i < 8; i++){ v[i] = __expf(v[i] - mx); sum += v[i]; }
    #pragma unroll
    for (int off = 32; off > 0; off >>= 1) sum += __shfl_xor(sum, off);
    if (lane == 0) red[4 + w] = sum;
    __syncthreads();
    sum = red[4] + red[5] + red[6] + red[7];
    float inv = 1.f / sum;

    #pragma unroll
    for (int i = 0; i < 8; i++){
        float p = v[i] * inv;
        u16 h, l; split_h(p, h, l);
        int m = tid + i*256;
        int ms = swz(n, m);
        Sh[n*2048 + ms] = h;
        Sl[n*2048 + ms] = l;
    }
}

// =====================================================================
// K2: prep — weight pools -> [jc][d][o][k] SINGLE f16, biases E@bpool,
// X_gate^T pack (single f16, chunk-swizzled).
// =====================================================================
__global__ __launch_bounds__(256) void k_prep(const float* __restrict__ E,
    const float* __restrict__ gwp, const float* __restrict__ gbp,
    const float* __restrict__ uwp, const float* __restrict__ ubp,
    const float* __restrict__ x,   const float* __restrict__ state,
    u16* __restrict__ wg, u16* __restrict__ wu,
    float* __restrict__ bg, float* __restrict__ bu,
    u16* __restrict__ xt)
{
    long idx = (long)blockIdx.x*256 + threadIdx.x;
    if (idx < 491520){                               // gate w -> [jc][d][128 o][32 k]
        int kk = (int)(idx & 31);
        int o  = (int)((idx >> 5) & 127);
        int r2 = (int)(idx >> 12);                   // 0..119
        int d = r2 % 10, jc = r2 / 10;
        int j = jc*32 + kk;                          // 0..383
        int k = j >> 7, i = j & 127;
        float v = gwp[(((d*3 + k)*128) + i)*128 + o];
        wg[idx] = f2h(v);
    } else if (idx < 737280){                        // upd w -> [jc][d][64 o][32 k]
        long t = idx - 491520;
        int kk = (int)(t & 31);
        int o  = (int)((t >> 5) & 63);
        int r2 = (int)(t >> 11);                     // 0..119
        int d = r2 % 10, jc = r2 / 10;
        int j = jc*32 + kk;
        int k = j >> 7, i = j & 127;
        float v = uwp[(((d*3 + k)*128) + i)*64 + o];
        wu[t] = f2h(v);
    } else if (idx < 999424){                        // bias_g [2048][128]
        long t = idx - 737280; int n = (int)(t >> 7), o = (int)(t & 127);
        float s = 0.f;
        #pragma unroll
        for (int d = 0; d < 10; d++) s += E[n*10+d]*gbp[d*128+o];
        bg[t] = s;
    } else if (idx < 1130496){                       // bias_u [2048][64]
        long t = idx - 999424; int n = (int)(t >> 6), o = (int)(t & 63);
        float s = 0.f;
        #pragma unroll
        for (int d = 0; d < 10; d++) s += E[n*10+d]*ubp[d*64+o];
        bu[t] = s;
    } else if (idx < 5324800){                       // X_gate^T pack (single f16, swz)
        long t = idx - 1130496;
        int colG = (int)(t >> 11), m = (int)(t & 2047);
        int b = colG >> 7, c = colG & 127;
        float v = (c < 64) ? x[((long)(b*2048)+m)*64 + c]
                           : state[((long)(b*2048)+m)*64 + c - 64];
        xt[(long)colG*2048 + swz(colG, m)] = f2h(v);
    }
}

// =====================================================================
// Diffusion GEMM  C[i][j] = sum_k A[i][k] * Bt[j][k].
// f16 2-limb (A = S hi/lo, B single). v2 structure:
//  - BK=64, double-buffered LDS (64 KB), ONE barrier per 64-K step
//    (was 4): __syncthreads' vmcnt(0)+lgkmcnt(0) drain is the only wait.
//  - global_load_lds width-16 staging (no VGPR roundtrip, no ds_writes).
//  - arrays are chunk-swizzled by producers -> linear LDS dest + 2-way
//    (free) ds_read_b128 bank aliasing. Accumulation order identical to
//    v1 -> result bit-exact (absmax canary).
// =====================================================================
template<int EPI>
__global__ __launch_bounds__(256) void k_gemm(
    const u16* __restrict__ Ah, const u16* __restrict__ Al,
    const u16* __restrict__ Bt,
    u16* __restrict__ Ot, float* __restrict__ Orow,
    const u16* __restrict__ Xt)
{
    __shared__ __attribute__((aligned(16))) u16 AsH[2][64*64];
    __shared__ __attribute__((aligned(16))) u16 AsL[2][64*64];
    __shared__ __attribute__((aligned(16))) u16 Bs[2][128*64];
    const int tid = threadIdx.x;
    const int bm = (blockIdx.x & 31) << 6;   // 32 row-tiles of 64 (node rows)
    const int bn = (blockIdx.x >> 5) << 7;   // 16 col-tiles of 128 (colG)
    const int w = tid >> 6, lane = tid & 63;
    const int wn = w << 5;                   // 32 cols per wave
    const int lr = lane & 15, lk = lane >> 4;

    // staging: thread t covers (row = t>>3 [+32..], phys chunk = t&7)
    const int srow = tid >> 3, scol = (tid & 7) << 3;
    const long a0 = (long)(bm + srow)*2048 + scol;
    const long a1 = a0 + 32*2048;
    const long b0 = (long)(bn + srow)*2048 + scol;
    const long b1 = b0 + 32*2048;
    const long b2 = b0 + 64*2048;
    const long b3 = b0 + 96*2048;
    const int l0 = tid*8, l1 = tid*8 + 2048;   // linear LDS dest (u16 units)

    // frag read: swizzled slot S = (s2*4 + lk) ^ (lr&7); u16 col = S*8
    const int c0 = (lk ^ (lr & 7)) << 3;
    const int c1 = c0 ^ 32;

#define STAGE(B, K) do { \
        gll16(Ah + a0 + (K), &AsH[B][l0]); \
        gll16(Ah + a1 + (K), &AsH[B][l1]); \
        gll16(Al + a0 + (K), &AsL[B][l0]); \
        gll16(Al + a1 + (K), &AsL[B][l1]); \
        gll16(Bt + b0 + (K), &Bs[B][l0]); \
        gll16(Bt + b1 + (K), &Bs[B][l1]); \
        gll16(Bt + b2 + (K), &Bs[B][l0 + 4096]); \
        gll16(Bt + b3 + (K), &Bs[B][l1 + 4096]); \
    } while(0)

    f32x4 acc[4][2];
    const f32x4 Z4 = {0.f, 0.f, 0.f, 0.f};
    #pragma unroll
    for (int i = 0; i < 4; i++)
        #pragma unroll
        for (int j = 0; j < 2; j++) acc[i][j] = Z4;

    STAGE(0, 0);
    __syncthreads();               // vmcnt(0) drain: buf0 ready
    int cur = 0;
    for (int k0 = 0; k0 < 2048; k0 += 64){
        if (k0 + 64 < 2048) STAGE(cur ^ 1, k0 + 64);   // async into other buf
        const u16* ah = AsH[cur];
        const u16* al = AsL[cur];
        const u16* bs = Bs[cur];
        #pragma unroll
        for (int s2 = 0; s2 < 2; s2++){
            const int cc = s2 ? c1 : c0;
            s16x8 bfv[2], af[4];
            #pragma unroll
            for (int ni = 0; ni < 2; ni++)
                bfv[ni] = *(const s16x8*)&bs[(wn + ni*16 + lr)*64 + cc];
            #pragma unroll
            for (int mi = 0; mi < 4; mi++)
                af[mi] = *(const s16x8*)&ah[(mi*16 + lr)*64 + cc];
            #pragma unroll
            for (int mi = 0; mi < 4; mi++)
                #pragma unroll
                for (int ni = 0; ni < 2; ni++)
                    acc[mi][ni] = mfma16(af[mi], bfv[ni], acc[mi][ni]);
            #pragma unroll
            for (int mi = 0; mi < 4; mi++)
                af[mi] = *(const s16x8*)&al[(mi*16 + lr)*64 + cc];
            #pragma unroll
            for (int mi = 0; mi < 4; mi++)
                #pragma unroll
                for (int ni = 0; ni < 2; ni++)
                    acc[mi][ni] = mfma16(af[mi], bfv[ni], acc[mi][ni]);
        }
        __syncthreads();           // all reads done + other buf's loads landed
        cur ^= 1;
    }
#undef STAGE

    #pragma unroll
    for (int mi = 0; mi < 4; mi++){
        #pragma unroll
        for (int ni = 0; ni < 2; ni++){
            int i0 = bm + mi*16 + lk*4;          // node (4 consecutive)
            int j  = bn + wn + ni*16 + lr;       // colG
            f32x4 v = acc[mi][ni];
            if constexpr (EPI){
                u16x4 xh = *(const u16x4*)(Xt + (long)j*2048 + swz(j, i0));
                #pragma unroll
                for (int r = 0; r < 4; r++)
                    v[r] = 2.f*v[r] - h2f(xh[r]);
            }
            int bb = j >> 7, cc = j & 127;
            float* rp = Orow + ((long)bb*2048 + i0)*128 + cc;
            #pragma unroll
            for (int r = 0; r < 4; r++) rp[(long)r*128] = v[r];
            if constexpr (!EPI){
                u16x4 oh;
                #pragma unroll
                for (int r = 0; r < 4; r++) oh[r] = f2h(v[r]);
                *(u16x4*)(Ot + (long)j*2048 + swz(j, i0)) = oh;
            }
        }
    }
}

// =====================================================================
// Combine (round-0 proven structure, f16 2-limb): out = sum_jc sum_d
// E[n,d]*(A_jc W[d]_jc) + bias. 256 thr, (256,2), d fully unrolled,
// triple-buffer W prefetch dist 2, zero-C first MFMA.
// =====================================================================
template<int OFULL, int ACT>
__global__ __launch_bounds__(256, 2) void k_combine(
    const float* __restrict__ G1r, const float* __restrict__ G2r,
    const float* __restrict__ x, const float* __restrict__ second,
    const u16* __restrict__ W,
    const float* __restrict__ bias, const float* __restrict__ E,
    float* __restrict__ out)
{
    constexpr int NO = OFULL/32;                 // o-frags per wave (4 gate, 2 upd)
    __shared__ u16 Ash[64*40], Asl[64*40];
    __shared__ float Et[640];
    const int tid = threadIdx.x, bid = blockIdx.x;
    const int b = bid >> 5, n0 = (bid & 31) << 6;
    const int w = tid >> 6, lane = tid & 63;
    const int wm = (w & 1)*32, wo = (w >> 1)*(OFULL/2);
    const int lr = lane & 15, lk = lane >> 4;

    for (int i = tid; i < 640; i += 256)
        Et[i] = E[(n0 + (i & 63))*10 + (i >> 6)];

    const f32x4 Z4 = {0.f, 0.f, 0.f, 0.f};
    f32x4 acc[2][NO];
    #pragma unroll
    for (int mi = 0; mi < 2; mi++)
        #pragma unroll
        for (int oi = 0; oi < NO; oi++) acc[mi][oi] = Z4;

    const long rowbase = (long)b*2048 + n0;
    const int laneoff = (wo + lr)*32 + lk*8;     // u16 offset within tile

    s16x8 pbh[3][NO];

    for (int jc = 0; jc < 12; jc++){
        // preload W tiles d=0,1 (independent of A; overlap staging+barrier)
        {
            const long t0 = (long)(jc*10 + 0)*OFULL*32;
            const long t1 = (long)(jc*10 + 1)*OFULL*32;
            #pragma unroll
            for (int oi = 0; oi < NO; oi++){
                pbh[0][oi] = *(const s16x8*)(W + t0 + laneoff + oi*16*32);
                pbh[1][oi] = *(const s16x8*)(W + t1 + laneoff + oi*16*32);
            }
        }
        __syncthreads();   // prior jc's A-frag reads are long done
        // ---- stage A (one 16B chunk per thread, f16 hi/lo) ----
        {
            const float* src; int stride;
            if (jc < 4){
                int col0 = jc*32;
                src = (col0 < 64) ? (x + rowbase*64 + col0)
                                  : (second + rowbase*64 + (col0 - 64));
                stride = 64;
            } else if (jc < 8){
                src = G1r + rowbase*128 + (jc-4)*32; stride = 128;
            } else {
                src = G2r + rowbase*128 + (jc-8)*32; stride = 128;
            }
            int row = tid >> 2, c8 = (tid & 3)*8;
            f32x4 s0 = *(const f32x4*)(src + (long)row*stride + c8);
            f32x4 s1 = *(const f32x4*)(src + (long)row*stride + c8 + 4);
            s16x8 vh, vl;
            #pragma unroll
            for (int t = 0; t < 4; t++){
                u16 h,l; split_h(s0[t], h, l); vh[t]=(short)h; vl[t]=(short)l;
            }
            #pragma unroll
            for (int t = 0; t < 4; t++){
                u16 h,l; split_h(s1[t], h, l); vh[4+t]=(short)h; vl[4+t]=(short)l;
            }
            *(s16x8*)&Ash[row*40 + c8] = vh;
            *(s16x8*)&Asl[row*40 + c8] = vl;
        }
        __syncthreads();

        s16x8 ah[2], al[2];
        #pragma unroll
        for (int mi = 0; mi < 2; mi++){
            ah[mi] = *(const s16x8*)&Ash[(wm + mi*16 + lr)*40 + lk*8];
            al[mi] = *(const s16x8*)&Asl[(wm + mi*16 + lr)*40 + lk*8];
        }

        #pragma unroll
        for (int d = 0; d < 10; d++){
            const int cur = d % 3;               // compile-time after unroll
            if (d < 8){                          // prefetch d+2 into slot (d+2)%3
                const int nx = (d + 2) % 3;
                const long t2 = (long)(jc*10 + d + 2)*OFULL*32;
                #pragma unroll
                for (int oi = 0; oi < NO; oi++)
                    pbh[nx][oi] = *(const s16x8*)(W + t2 + laneoff + oi*16*32);
            }
            f32x4 Cd[2][NO];
            #pragma unroll
            for (int mi = 0; mi < 2; mi++)
                #pragma unroll
                for (int oi = 0; oi < NO; oi++)
                    Cd[mi][oi] = mfma16(ah[mi], pbh[cur][oi], Z4);
            #pragma unroll
            for (int mi = 0; mi < 2; mi++)
                #pragma unroll
                for (int oi = 0; oi < NO; oi++)
                    Cd[mi][oi] = mfma16(al[mi], pbh[cur][oi], Cd[mi][oi]);
            #pragma unroll
            for (int mi = 0; mi < 2; mi++){
                f32x4 e4 = *(const f32x4*)&Et[d*64 + wm + mi*16 + lk*4];
                #pragma unroll
                for (int oi = 0; oi < NO; oi++) acc[mi][oi] += e4 * Cd[mi][oi];
            }
        }
    }

    #pragma unroll
    for (int mi = 0; mi < 2; mi++){
        #pragma unroll
        for (int oi = 0; oi < NO; oi++){
            int mrow = n0 + wm + mi*16 + lk*4;
            int o = wo + oi*16 + lr;
            #pragma unroll
            for (int r = 0; r < 4; r++){
                float v = acc[mi][oi][r] + bias[(long)(mrow + r)*OFULL + o];
                v = (ACT == 0) ? (1.f/(1.f + __expf(-v))) : tanhf(v);
                out[((long)b*2048 + mrow + r)*OFULL + o] = v;
            }
        }
    }
}

// =====================================================================
// K6: zr = Zg @ lin_w^T + lin_b
// =====================================================================
__global__ __launch_bounds__(256) void k_lin(const float* __restrict__ Zg,
                                             const float* __restrict__ lw,
                                             const float* __restrict__ lb,
                                             float* __restrict__ zr)
{
    __shared__ float wl[64*132];
    const int tid = threadIdx.x;
    for (int i = tid; i < 8192; i += 256) wl[(i >> 7)*132 + (i & 127)] = lw[i];
    __syncthreads();
    int gid = blockIdx.x*256 + tid;
    int row = gid >> 3, og = (gid & 7) << 3;
    float a[8];
    #pragma unroll
    for (int t = 0; t < 8; t++) a[t] = lb[og + t];
    const float* zrow = Zg + (long)row*128;
    #pragma unroll
    for (int jc = 0; jc < 8; jc++){
        f32x4 x0 = *(const f32x4*)(zrow + jc*16);
        f32x4 x1 = *(const f32x4*)(zrow + jc*16 + 4);
        f32x4 x2 = *(const f32x4*)(zrow + jc*16 + 8);
        f32x4 x3 = *(const f32x4*)(zrow + jc*16 + 12);
        #pragma unroll
        for (int t = 0; t < 8; t++){
            const float* wr = &wl[(og + t)*132 + jc*16];
            f32x4 w0 = *(const f32x4*)(wr);
            f32x4 w1 = *(const f32x4*)(wr + 4);
            f32x4 w2 = *(const f32x4*)(wr + 8);
            f32x4 w3 = *(const f32x4*)(wr + 12);
            f32x4 p = x0*w0 + x1*w1 + x2*w2 + x3*w3;
            a[t] += p[0] + p[1] + p[2] + p[3];
        }
    }
    #pragma unroll
    for (int t = 0; t < 8; t++) zr[(long)row*64 + og + t] = a[t];
}

// =====================================================================
// K7: pack candidate^T [colG][m] single f16 (chunk-swizzled) from x | zr
// =====================================================================
__global__ __launch_bounds__(256) void k_packu(const float* __restrict__ x,
                                               const float* __restrict__ zr,
                                               u16* __restrict__ T)
{
    int idx = blockIdx.x*256 + threadIdx.x;
    int colG = idx >> 11, m = idx & 2047;
    int b = colG >> 7, c = colG & 127;
    float v = (c < 64) ? x[((long)(b*2048) + m)*64 + c]
                       : zr[((long)(b*2048) + m)*64 + c - 64];
    T[(long)colG*2048 + swz(colG, m)] = f2h(v);
}

// =====================================================================
extern "C" void kernel_launch(void* const* d_in, const int* in_sizes, int n_in,
                              void* d_out, int out_size, void* d_ws, size_t ws_size,
                              hipStream_t stream)
{
    const float* x   = (const float*)d_in[0];
    const float* st  = (const float*)d_in[1];
    const float* E   = (const float*)d_in[2];
    const float* gwp = (const float*)d_in[3];
    const float* gbp = (const float*)d_in[4];
    const float* uwp = (const float*)d_in[5];
    const float* ubp = (const float*)d_in[6];
    const float* lw  = (const float*)d_in[7];
    const float* lb  = (const float*)d_in[8];
    float* out = (float*)d_out;
    char* ws = (char*)d_ws;

    const size_t MB8 = 8388608;
    u16*   Sh   = (u16*)(ws);                 // 8 MB
    u16*   Sl   = (u16*)(ws + 1*MB8);         // 8 MB
    u16*   Xt   = (u16*)(ws + 2*MB8);         // 8 MB  (single f16 X^T / candidate^T)
    u16*   G1t  = (u16*)(ws + 3*MB8);         // 8 MB  (single f16 G1^T)
    float* G1row= (float*)(ws + 4*MB8);       // 16 MB
    float* G2row= (float*)(ws + 6*MB8);       // 16 MB
    float* Zg   = (float*)(ws + 8*MB8);       // 16 MB
    float* zr   = (float*)(ws + 10*MB8);      // 8 MB
    char*  p    = ws + 11*MB8;
    u16* wg = (u16*)p;             p += 983040;
    u16* wu = (u16*)p;             p += 491520;
    float* bg = (float*)p;         p += 1048576;
    float* bu = (float*)p;         p += 524288;

    k_supports<<<dim3(2048), dim3(256), 0, stream>>>(E, Sh, Sl);
    k_prep<<<dim3(20800), dim3(256), 0, stream>>>(E, gwp, gbp, uwp, ubp, x, st,
                                                  wg, wu, bg, bu, Xt);
    // gate diffusion
    k_gemm<0><<<dim3(512), dim3(256), 0, stream>>>(Sh, Sl, Xt, G1t, G1row,
                                                   (const u16*)nullptr);
    k_gemm<1><<<dim3(512), dim3(256), 0, stream>>>(Sh, Sl, G1t, (u16*)nullptr, G2row,
                                                   Xt);
    // gate combine -> Zg (sigmoid)
    k_combine<128,0><<<dim3(512), dim3(256), 0, stream>>>(G1row, G2row, x, st,
                                                          wg, bg, E, Zg);
    k_lin<<<dim3(1024), dim3(256), 0, stream>>>(Zg, lw, lb, zr);
    k_packu<<<dim3(16384), dim3(256), 0, stream>>>(x, zr, Xt);
    // update diffusion
    k_gemm<0><<<dim3(512), dim3(256), 0, stream>>>(Sh, Sl, Xt, G1t, G1row,
                                                   (const u16*)nullptr);
    k_gemm<1><<<dim3(512), dim3(256), 0, stream>>>(Sh, Sl, G1t, (u16*)nullptr, G2row,
                                                   Xt);
    // update combine -> out (tanh)
    k_combine<64,1><<<dim3(512), dim3(256), 0, stream>>>(G1row, G2row, x, zr,
                                                         wu, bu, E, out);
}